// Round 8
// baseline (164.676 us; speedup 1.0000x reference)
//
#include <hip/hip_runtime.h>
#include <cstdint>
#include <cstddef>

#define BB 32
#define TT 14
#define DD 1024
#define RR 4
#define VV 8192
#define NCOL (VV*RR*RR)   // 131072 columns
#define COLS 512          // columns per block
#define NTHR 512          // threads per block (8 waves)

typedef float f32x16 __attribute__((ext_vector_type(16)));
typedef float f4 __attribute__((ext_vector_type(4)));
typedef short short8 __attribute__((ext_vector_type(8)));
typedef unsigned int uint;

// ws layout (floats):
//  cm    : B*16   = 512   @ 0
//  sel   : B*T*16 = 7168  @ 512
//  alpha : B*4    = 128   @ 7680
//  beta  : B*4    = 128   @ 7808
//  xfrag : 8192 uint4     @ 7936   (A-fragments, bf16, 128 KB)

// pack hi16(a) | hi16(b)<<16  (bf16 truncation via byte-perm)
__device__ __forceinline__ uint pack2(float a, float b) {
    return __builtin_amdgcn_perm(__builtin_bit_cast(uint, b),
                                 __builtin_bit_cast(uint, a), 0x07060302u);
}

__device__ __forceinline__ short8 packw(const float* w) {
    uint4 u = make_uint4(pack2(w[0], w[1]), pack2(w[2], w[3]),
                         pack2(w[4], w[5]), pack2(w[6], w[7]));
    return __builtin_bit_cast(short8, u);
}

// One block per b: mean over T -> LDS; emit xfrag slice; alpha/beta dots; zero cm.
__global__ __launch_bounds__(256) void k_prep_all(const float* __restrict__ in,
                                                  const float* __restrict__ wa,
                                                  const float* __restrict__ wb,
                                                  ushort* __restrict__ xfrag_us,
                                                  float* __restrict__ alpha,
                                                  float* __restrict__ beta,
                                                  float* __restrict__ cm) {
    __shared__ float xl[DD];
    const int b   = blockIdx.x;
    const int tid = threadIdx.x;
    const int d0  = tid * 4;

    f4 s4 = (f4){0.f, 0.f, 0.f, 0.f};
    #pragma unroll
    for (int t = 0; t < TT; ++t) {
        f4 v = *reinterpret_cast<const f4*>(&in[((b * TT + t) << 10) + d0]);
        s4 += v;
    }
    s4 *= (1.0f / TT);
    *reinterpret_cast<f4*>(&xl[d0]) = s4;

    if (b == 0) { cm[tid] = 0.f; cm[tid + 256] = 0.f; }

    // xfrag: lane l = b + 32*h holds k = s*16 + h*8 + j  (j=0..7) of step s
    {
        const int s  = d0 >> 4;
        const int h  = (d0 >> 3) & 1;
        const int j0 = d0 & 7;           // 0 or 4
        uint2 u;
        u.x = pack2(s4.x, s4.y);
        u.y = pack2(s4.z, s4.w);
        *reinterpret_cast<uint2*>(&xfrag_us[((s * 64 + b + 32 * h) << 3) + j0]) = u;
    }

    __syncthreads();

    const int wave = tid >> 6, lane = tid & 63;
    for (int p = wave; p < 8; p += 4) {
        const int r = p >> 1, sf = p & 1;
        const float* wm = sf ? wb : wa;
        float acc = 0.f;
        #pragma unroll
        for (int k = 0; k < 16; ++k) {
            int d = lane + 64 * k;
            acc += xl[d] * wm[d * RR + r];
        }
        #pragma unroll
        for (int m = 1; m < 64; m <<= 1) acc += __shfl_xor(acc, m);
        if (lane == 0) {
            float v = 1.0f / (1.0f + __expf(-acc)) + 0.001f;
            (sf ? beta : alpha)[b * RR + r] = v;
        }
    }
}

// Stage 16 rows x 512 cols f32 (32 KB) of step SG into buf[SG&3] + load ax(SG).
// Per wave: exactly 5 VMEM ops (4 global_load_lds dwordx4 + 1 dwordx4).
#define STAGE(SG, AXREG)                                                      \
    do {                                                                      \
        const int bi_ = (SG) & 3;                                             \
        _Pragma("unroll")                                                     \
        for (int r_ = 0; r_ < 4; ++r_) {                                      \
            const float* gp_ = wv + (size_t)(16 * (SG) + 4 * r_ + srow) * NCOL\
                               + n0 + scol;                                   \
            __builtin_amdgcn_global_load_lds(                                 \
                (const __attribute__((address_space(1))) void*)gp_,           \
                (__attribute__((address_space(3))) void*)                     \
                    &buf[bi_][4 * r_ + srow][scol],                           \
                16, 0, 0);                                                    \
        }                                                                     \
        AXREG = xf[((SG) << 6) + lane];                                       \
    } while (0)

// 2 MFMA tiles (64 cols) for step SG from buf[SG&3].
#define COMPUTE(SG, AXREG)                                                    \
    do {                                                                      \
        const int bi_ = (SG) & 3;                                             \
        _Pragma("unroll")                                                     \
        for (int tau_ = 0; tau_ < 2; ++tau_) {                                \
            float wr_[8];                                                     \
            _Pragma("unroll")                                                 \
            for (int j_ = 0; j_ < 8; ++j_)                                    \
                wr_[j_] = buf[bi_][rbase + j_][cloc + tau_ * 32];             \
            acc[tau_] = __builtin_amdgcn_mfma_f32_32x32x16_bf16(              \
                __builtin_bit_cast(short8, AXREG), packw(wr_), acc[tau_],     \
                0, 0, 0);                                                     \
        }                                                                     \
    } while (0)

#define VMWAIT(N) asm volatile("s_waitcnt vmcnt(" #N ")" ::: "memory")
#define BAR()     __builtin_amdgcn_s_barrier()

// Block: 512 threads / 8 waves, 512 columns, K staged through LDS.
// 4-buffer rotation, depth-2 prefetch, counted vmcnt (never 0 in loop).
__global__ __launch_bounds__(512, 2) void k_core(const float* __restrict__ wv,
                                                 const uint4* __restrict__ xfrag,
                                                 const int*   __restrict__ lab,
                                                 float* __restrict__ cm,
                                                 float* __restrict__ sel) {
    const int tid  = threadIdx.x;
    const int lane = tid & 63;
    const int w    = tid >> 6;            // wave 0..7
    const int n0   = blockIdx.x * COLS;   // block column base
    const int ii   = n0 >> 15;            // r1 block (uniform)

    __shared__ __align__(16) char smem[4 * 16 * COLS * 4];   // 128 KB
    auto buf = reinterpret_cast<float(*)[16][COLS]>(smem);   // buf[4][16][512]

    // staging geometry: round r -> rows 4r + (tid>>7), 2 KB contiguous per row
    const int srow = tid >> 7;            // 0..3
    const int scol = (tid & 127) << 2;    // float index, 16 B per thread
    const uint4* xf = xfrag;

    // fragment geometry
    const int rbase = (lane >> 5) * 8;            // k-row base 0/8
    const int cloc  = w * 64 + (lane & 31);       // local col, tile 0

    f32x16 acc[2];
    #pragma unroll
    for (int t = 0; t < 2; ++t)
        #pragma unroll
        for (int q = 0; q < 16; ++q) acc[t][q] = 0.f;

    uint4 ax0, ax1, ax2, ax3;
    STAGE(0, ax0);
    STAGE(1, ax1);

    #pragma unroll 1
    for (int s = 0; s < 56; s += 4) {
        STAGE(s + 2, ax2); VMWAIT(10); BAR(); COMPUTE(s,     ax0);
        STAGE(s + 3, ax3); VMWAIT(10); BAR(); COMPUTE(s + 1, ax1);
        STAGE(s + 4, ax0); VMWAIT(10); BAR(); COMPUTE(s + 2, ax2);
        STAGE(s + 5, ax1); VMWAIT(10); BAR(); COMPUTE(s + 3, ax3);
    }
    STAGE(58, ax2); VMWAIT(10); BAR(); COMPUTE(56, ax0);
    STAGE(59, ax3); VMWAIT(10); BAR(); COMPUTE(57, ax1);
    STAGE(60, ax0); VMWAIT(10); BAR(); COMPUTE(58, ax2);
    STAGE(61, ax1); VMWAIT(10); BAR(); COMPUTE(59, ax3);
    STAGE(62, ax2); VMWAIT(10); BAR(); COMPUTE(60, ax0);
    STAGE(63, ax3); VMWAIT(10); BAR(); COMPUTE(61, ax1);
    VMWAIT(5);  BAR(); COMPUTE(62, ax2);
    VMWAIT(0);  BAR(); COMPUTE(63, ax3);

    // reuse smem for labels + block cm accumulator (buf is dead)
    __syncthreads();
    int*   lds_lab = reinterpret_cast<int*>(smem);
    float* cm_blk  = reinterpret_cast<float*>(smem) + BB * TT;
    for (int idx = tid; idx < BB * TT; idx += NTHR) lds_lab[idx] = lab[idx];
    if (tid < BB * 4) cm_blk[tid] = 0.f;
    __syncthreads();

    #pragma unroll
    for (int tau = 0; tau < 2; ++tau) {
        const int n  = n0 + w * 64 + tau * 32 + (lane & 31);
        const int jj = n & 3;
        const int vv = (n >> 2) & (VV - 1);
        #pragma unroll
        for (int r = 0; r < 16; ++r) {
            float c = 0.01f / (1.0f + __expf(-acc[tau][r])) + 0.001f;
            const int b = (r & 3) + 8 * (r >> 2) + 4 * (lane >> 5);
            float sred = c;
            sred += __shfl_xor(sred, 4);
            sred += __shfl_xor(sred, 8);
            sred += __shfl_xor(sred, 16);
            if ((lane & 31) < 4) atomicAdd(&cm_blk[b * 4 + (lane & 3)], sred);
            #pragma unroll
            for (int t = 0; t < TT; ++t)
                if (lds_lab[b * TT + t] == vv)
                    sel[(b * TT + t) * 16 + (ii << 2) + jj] = c;
        }
    }
    __syncthreads();
    if (tid < BB * 4)
        atomicAdd(&cm[(tid >> 2) * 16 + (ii << 2) + (tid & 3)], cm_blk[tid]);
}

__global__ __launch_bounds__(64) void k_final(const float* __restrict__ cm,
                                              const float* __restrict__ sel,
                                              const float* __restrict__ alpha,
                                              const float* __restrict__ beta,
                                              float* __restrict__ out) {
    __shared__ float ls[BB];
    int b = threadIdx.x;
    if (b < BB) {
        float ch[16], tmp[16];
        #pragma unroll
        for (int q = 0; q < 16; ++q) ch[q] = sel[(b * TT + 0) * 16 + q];
        for (int t = 1; t < TT; ++t) {
            const float* m = &sel[(b * TT + t) * 16];
            #pragma unroll
            for (int i2 = 0; i2 < 4; ++i2)
                #pragma unroll
                for (int j2 = 0; j2 < 4; ++j2) {
                    float s = 0.f;
                    #pragma unroll
                    for (int k = 0; k < 4; ++k) s += ch[i2*4+k] * m[k*4+j2];
                    tmp[i2*4+j2] = s;
                }
            #pragma unroll
            for (int q = 0; q < 16; ++q) ch[q] = tmp[q];
        }

        float M[16], P[16];
        #pragma unroll
        for (int q = 0; q < 16; ++q) { M[q] = cm[b*16+q]; P[q] = M[q]; }
        for (int t = 0; t < TT; ++t) {   // P = cm^(T+1)
            #pragma unroll
            for (int i2 = 0; i2 < 4; ++i2)
                #pragma unroll
                for (int j2 = 0; j2 < 4; ++j2) {
                    float s = 0.f;
                    #pragma unroll
                    for (int k = 0; k < 4; ++k) s += P[i2*4+k] * M[k*4+j2];
                    tmp[i2*4+j2] = s;
                }
            #pragma unroll
            for (int q = 0; q < 16; ++q) P[q] = tmp[q];
        }

        float a[4], be[4];
        #pragma unroll
        for (int r = 0; r < 4; ++r) { a[r] = alpha[b*4+r]; be[r] = beta[b*4+r]; }
        float un = 0.f, no = 0.f;
        #pragma unroll
        for (int i2 = 0; i2 < 4; ++i2)
            #pragma unroll
            for (int j2 = 0; j2 < 4; ++j2) {
                un += a[i2] * ch[i2*4+j2] * be[j2];
                no += a[i2] * P [i2*4+j2] * be[j2];
            }
        float prob = un / no + 0.001f;
        ls[b] = -logf(prob);
    }
    __syncthreads();
    if (threadIdx.x == 0) {
        float s = 0.f;
        for (int q = 0; q < BB; ++q) s += ls[q];
        out[0] = s / BB;
    }
}

extern "C" void kernel_launch(void* const* d_in, const int* in_sizes, int n_in,
                              void* d_out, int out_size, void* d_ws, size_t ws_size,
                              hipStream_t stream) {
    const float* in_embs = (const float*)d_in[0];
    const int*   lab     = (const int*)  d_in[1];
    const float* wa      = (const float*)d_in[2];
    const float* wb      = (const float*)d_in[3];
    const float* wv      = (const float*)d_in[4];

    float* ws    = (float*)d_ws;
    float* cm    = ws;
    float* sel   = ws + 512;
    float* alpha = ws + 7680;
    float* beta  = ws + 7808;
    uint4* xfrag = (uint4*)(ws + 7936);

    k_prep_all<<<32,  256, 0, stream>>>(in_embs, wa, wb, (ushort*)xfrag,
                                        alpha, beta, cm);
    k_core    <<<256, NTHR, 0, stream>>>(wv, xfrag, lab, cm, sel);
    k_final   <<<1,   64,  0, stream>>>(cm, sel, alpha, beta, (float*)d_out);
}